// Round 1
// baseline (270.984 us; speedup 1.0000x reference)
//
#include <hip/hip_runtime.h>

// out[i]        = p[i]                          for i in [0, SIZE)
// out[SIZE + i] = w[i] * selu(p[i]) + q[i]      q = x[SIZE + i]
//
// Memory-bound: 320 MB total traffic. One thread per float4 of the half-array.

__global__ void __launch_bounds__(256)
activation_moduleA_48112223650431_kernel(const float4* __restrict__ x4,
                                         const float4* __restrict__ w4,
                                         float4* __restrict__ out4,
                                         int n4 /* = SIZE/4 */) {
    int i = blockIdx.x * blockDim.x + threadIdx.x;
    if (i >= n4) return;

    float4 p = x4[i];        // first half of x
    float4 q = x4[n4 + i];   // second half of x
    float4 w = w4[i];

    const float scale = 1.0507009873554805f;
    const float alpha = 1.6732632423543773f;

    float4 r;
    {
        float s = p.x > 0.f ? p.x : alpha * (__expf(p.x) - 1.f);
        r.x = w.x * (scale * s) + q.x;
    }
    {
        float s = p.y > 0.f ? p.y : alpha * (__expf(p.y) - 1.f);
        r.y = w.y * (scale * s) + q.y;
    }
    {
        float s = p.z > 0.f ? p.z : alpha * (__expf(p.z) - 1.f);
        r.z = w.z * (scale * s) + q.z;
    }
    {
        float s = p.w > 0.f ? p.w : alpha * (__expf(p.w) - 1.f);
        r.w = w.w * (scale * s) + q.w;
    }

    out4[i]      = p;  // copy-through first half
    out4[n4 + i] = r;  // gated residual second half
}

extern "C" void kernel_launch(void* const* d_in, const int* in_sizes, int n_in,
                              void* d_out, int out_size, void* d_ws, size_t ws_size,
                              hipStream_t stream) {
    const float4* x4 = (const float4*)d_in[0];
    const float4* w4 = (const float4*)d_in[1];
    float4* out4 = (float4*)d_out;

    int size = in_sizes[1];      // SIZE = N/2, 16777216
    int n4 = size / 4;           // 4194304 float4 elements per half

    int block = 256;
    int grid = (n4 + block - 1) / block;  // 16384 blocks
    activation_moduleA_48112223650431_kernel<<<grid, block, 0, stream>>>(x4, w4, out4, n4);
}